// Round 3
// baseline (599.598 us; speedup 1.0000x reference)
//
#include <hip/hip_runtime.h>
#include <stdint.h>

// Quant4-LUT matvec: y = x @ dequant(qweight, kmvalues)^T + bias
// qweight arrives as int32 (one 0..255 byte-code per element): (28672, 4096),
// 469.8 MB -> HBM-streaming, roofline ~75 us @ 6.3 TB/s.
//
// Structure (round 3): block owns 16 consecutive rows; each of the 4 waves
// owns a fixed QUARTER of every row. Low VGPR (~60) -> ~8 waves/SIMD; 1792
// blocks = 7/CU resident. No per-row barrier (wave-private LUTs, same-wave DS
// is in-order); ONE __syncthreads at the end before the 4-way combine.
// Per code: 1 ds_read_b32 (256-entry byte->half2 LUT, 2 copies per wave to
// halve random-index bank conflicts) + 1 v_dot2_f32_f16.

typedef _Float16 half2_t __attribute__((ext_vector_type(2)));

#define OUT_F   28672
#define ROW_E   4096                  // int32 codes per row
#define QTR     1024                  // codes per quarter-row (per wave)
#define NBLOCKS 1792
#define RPB     (OUT_F / NBLOCKS)     // 16 rows per block, exact

__device__ __forceinline__ float dot2acc(half2_t a, half2_t b, float c) {
#if __has_builtin(__builtin_amdgcn_fdot2)
    return __builtin_amdgcn_fdot2(a, b, c, false);
#else
    return c + (float)a.x * (float)b.x + (float)a.y * (float)b.y;
#endif
}

__global__ __launch_bounds__(256, 4) void q4lut_matvec(
    const float* __restrict__ x,
    const int*   __restrict__ qw,     // one code per int32
    const float* __restrict__ kmv,
    const float* __restrict__ bias,
    float* __restrict__ out)
{
    // Per-wave 256-entry byte->half2 LUT, duplicated per half-wave: 8 KiB.
    __shared__ uint32_t pairlut[4][2][256];
    __shared__ float    partial[RPB][4];

    const int tid  = threadIdx.x;
    const int wave = tid >> 6;
    const int lane = tid & 63;
    const int rowbase = blockIdx.x * RPB;

    // This lane's LUT copy (lanes 0-31 -> copy 0, 32-63 -> copy 1).
    const uint32_t* lut = &pairlut[wave][lane >> 5][0];

    // ---- Preload this wave's x slice (quarter of x), packed as 16 half2.
    // Code e (row-local) = wave*1024 + c*256 + lane*4 + k covers x[2e],x[2e+1]
    // -> floats x[wave*2048 + c*512 + lane*8 + 0..8) for c<4.
    half2_t xp[16];
#pragma unroll
    for (int c = 0; c < 4; ++c) {
        const float4* xs =
            reinterpret_cast<const float4*>(x + wave * 2048 + c * 512 + lane * 8);
        float4 v0 = xs[0];
        float4 v1 = xs[1];
        xp[c * 4 + 0] = half2_t{(_Float16)v0.x, (_Float16)v0.y};
        xp[c * 4 + 1] = half2_t{(_Float16)v0.z, (_Float16)v0.w};
        xp[c * 4 + 2] = half2_t{(_Float16)v1.x, (_Float16)v1.y};
        xp[c * 4 + 3] = half2_t{(_Float16)v1.z, (_Float16)v1.w};
    }

    for (int r = 0; r < RPB; ++r) {
        const int row = rowbase + r;

        // ---- Issue this wave's quarter-row code loads (4 KiB, 4x dwordx4).
        const uint4* q4 = reinterpret_cast<const uint4*>(
            qw + (size_t)row * ROW_E + wave * QTR);
        uint4 cs0 = q4[0 * 64 + lane];
        uint4 cs1 = q4[1 * 64 + lane];
        uint4 cs2 = q4[2 * 64 + lane];
        uint4 cs3 = q4[3 * 64 + lane];

        // ---- Build byte->pair LUT from L1-hot kmv row (no bpermute, no
        // barrier: LUT is wave-private, same-wave DS executes in order).
        // Entry e = lane*4+k: lo = kr[e & 15] = kr[(lane&3)*4 + k],
        //                     hi = kr[e >> 4] = kr[lane >> 2].
        const float* kr = kmv + row * 16;
        const float  hif = kr[lane >> 2];
        const float4 lo4 = reinterpret_cast<const float4*>(kr)[lane & 3];
        const _Float16 hih = (_Float16)hif;
        uint32_t e0 = __builtin_bit_cast(uint32_t, half2_t{(_Float16)lo4.x, hih});
        uint32_t e1 = __builtin_bit_cast(uint32_t, half2_t{(_Float16)lo4.y, hih});
        uint32_t e2 = __builtin_bit_cast(uint32_t, half2_t{(_Float16)lo4.z, hih});
        uint32_t e3 = __builtin_bit_cast(uint32_t, half2_t{(_Float16)lo4.w, hih});
        uint4 ent = make_uint4(e0, e1, e2, e3);
        *reinterpret_cast<uint4*>(&pairlut[wave][0][lane * 4]) = ent;
        *reinterpret_cast<uint4*>(&pairlut[wave][1][lane * 4]) = ent;

        // ---- Hot loop: 16 codes/lane, 1 ds_read_b32 + 1 fdot2 each.
        float acc = 0.f;
        const uint4 cs[4] = {cs0, cs1, cs2, cs3};
#pragma unroll
        for (int c = 0; c < 4; ++c) {
            const uint32_t d0 = cs[c].x, d1 = cs[c].y, d2 = cs[c].z, d3 = cs[c].w;
            acc = dot2acc(xp[c * 4 + 0], __builtin_bit_cast(half2_t, lut[d0 & 0xffu]), acc);
            acc = dot2acc(xp[c * 4 + 1], __builtin_bit_cast(half2_t, lut[d1 & 0xffu]), acc);
            acc = dot2acc(xp[c * 4 + 2], __builtin_bit_cast(half2_t, lut[d2 & 0xffu]), acc);
            acc = dot2acc(xp[c * 4 + 3], __builtin_bit_cast(half2_t, lut[d3 & 0xffu]), acc);
        }

        // ---- Wave-reduce, stash this wave's partial for the row.
#pragma unroll
        for (int off = 32; off > 0; off >>= 1)
            acc += __shfl_xor(acc, off, 64);
        if (lane == 0) partial[r][wave] = acc;
    }

    __syncthreads();

    // ---- Combine the 4 wave-partials per row + bias, store.
    if (tid < RPB) {
        const int row = rowbase + tid;
        out[row] = partial[tid][0] + partial[tid][1] +
                   partial[tid][2] + partial[tid][3] + bias[row];
    }
}

extern "C" void kernel_launch(void* const* d_in, const int* in_sizes, int n_in,
                              void* d_out, int out_size, void* d_ws, size_t ws_size,
                              hipStream_t stream) {
    const float* x    = (const float*)d_in[0];
    const int*   qw   = (const int*)d_in[1];
    const float* kmv  = (const float*)d_in[2];
    const float* bias = (const float*)d_in[3];
    float*       out  = (float*)d_out;

    hipLaunchKernelGGL(q4lut_matvec, dim3(NBLOCKS), dim3(256), 0, stream,
                       x, qw, kmv, bias, out);
}